// Round 1
// baseline (140.518 us; speedup 1.0000x reference)
//
#include <hip/hip_runtime.h>
#include <hip/hip_bf16.h>

typedef __bf16 bf16;
typedef __attribute__((ext_vector_type(8))) __bf16 bf16x8;
typedef __attribute__((ext_vector_type(4))) __bf16 bf16x4;
typedef __attribute__((ext_vector_type(4))) float f32x4;

__device__ __forceinline__ void async_load16(const void* g, void* l) {
    __builtin_amdgcn_global_load_lds(
        (const __attribute__((address_space(1))) void*)g,
        (__attribute__((address_space(3))) void*)l, 16, 0, 0);
}

// ---------- kernel 1: per-block partial sum of |w| (deterministic tree) ----------
__global__ __launch_bounds__(256) void k_abs_part(const float* __restrict__ w, int n,
                                                  double* __restrict__ part) {
    __shared__ double sd[256];
    const int per_block = n / gridDim.x;
    const int base = blockIdx.x * per_block;
    double s = 0.0;
    for (int i = threadIdx.x; i < per_block; i += 256)
        s += (double)fabsf(w[base + i]);
    sd[threadIdx.x] = s;
    __syncthreads();
    for (int off = 128; off > 0; off >>= 1) {
        if (threadIdx.x < off) sd[threadIdx.x] += sd[threadIdx.x + off];
        __syncthreads();
    }
    if (threadIdx.x == 0) part[blockIdx.x] = sd[0];
}

// ---------- kernel 2: finalize delta = 0.7 * mean(|w|) ----------
__global__ __launch_bounds__(256) void k_delta(const double* __restrict__ part, int npart,
                                               int n, float* __restrict__ delta) {
    __shared__ double sd[256];
    double s = 0.0;
    for (int i = threadIdx.x; i < npart; i += 256) s += part[i];
    sd[threadIdx.x] = s;
    __syncthreads();
    for (int off = 128; off > 0; off >>= 1) {
        if (threadIdx.x < off) sd[threadIdx.x] += sd[threadIdx.x + off];
        __syncthreads();
    }
    if (threadIdx.x == 0) *delta = (float)(0.7 * sd[0] / (double)n);
}

// ---------- kernel 3: ternary-quantize weight to bf16 {-1,0,1} ----------
__global__ __launch_bounds__(256) void k_quant(const float* __restrict__ w,
                                               const float* __restrict__ dp,
                                               bf16* __restrict__ wt, int n4) {
    const float d = *dp;
    const int i = blockIdx.x * 256 + threadIdx.x;
    if (i >= n4) return;
    const float4 v = ((const float4*)w)[i];
    bf16x4 o;
    o[0] = (bf16)((v.x > d) ? 1.0f : (v.x < -d) ? -1.0f : 0.0f);
    o[1] = (bf16)((v.y > d) ? 1.0f : (v.y < -d) ? -1.0f : 0.0f);
    o[2] = (bf16)((v.z > d) ? 1.0f : (v.z < -d) ? -1.0f : 0.0f);
    o[3] = (bf16)((v.w > d) ? 1.0f : (v.w < -d) ? -1.0f : 0.0f);
    *(bf16x4*)(wt + (size_t)i * 4) = o;
}

// ---------- kernel 4: GEMM  C[m][n] = alpha * sum_k A[m][k]*Wt[n][k] + bias[n] ----------
// 128x128 tile, BK=32, 256 threads = 4 waves (2x2), each wave 64x64 via 4x4 MFMA frags.
__global__ __launch_bounds__(256) void k_gemm(const float* __restrict__ A,
                                              const bf16* __restrict__ Bw,
                                              const float* __restrict__ alphap,
                                              const float* __restrict__ bias,
                                              float* __restrict__ C,
                                              int M, int N, int K) {
    __shared__ bf16 As[128 * 32];
    __shared__ bf16 Bs[128 * 32];

    const int t    = threadIdx.x;
    const int lane = t & 63;
    const int wave = t >> 6;
    const int nbm  = M >> 7;
    const int bm0  = (blockIdx.x % nbm) << 7;   // m-fastest: concurrent blocks stream A once
    const int bn0  = (blockIdx.x / nbm) << 7;
    const int wr   = (wave >> 1) << 6;          // wave row offset within tile
    const int wc   = (wave & 1) << 6;           // wave col offset within tile

    f32x4 acc[4][4] = {};

    const int lr = lane & 15;          // frag row (A) / frag col (B)
    const int lk = (lane >> 4) << 3;   // k-offset within BK: 0,8,16,24

    for (int k0 = 0; k0 < K; k0 += 32) {
        // ---- stage B (bf16 ternary weights) via global_load_lds, 16B/lane ----
        #pragma unroll
        for (int j = 0; j < 2; ++j) {
            const int c = t + j * 256;                       // chunk 0..511 (16B each)
            const bf16* src = Bw + (size_t)(bn0 + (c >> 2)) * K + k0 + ((c & 3) << 3);
            async_load16(src, (char*)Bs + j * 4096 + wave * 1024);  // wave-uniform base
        }
        // ---- stage A: fp32 -> bf16 reg-staged ----
        #pragma unroll
        for (int i = 0; i < 4; ++i) {
            const int idx = t + i * 256;                     // 1024 float4-chunks
            const int row = idx >> 3;
            const int c4  = (idx & 7) << 2;
            const float4 v = *(const float4*)(A + (size_t)(bm0 + row) * K + k0 + c4);
            bf16x4 h;
            h[0] = (bf16)v.x; h[1] = (bf16)v.y; h[2] = (bf16)v.z; h[3] = (bf16)v.w;
            *(bf16x4*)(As + row * 32 + c4) = h;
        }
        __syncthreads();   // drains vmcnt (global_load_lds) + lgkmcnt (ds_write)

        // ---- MFMA ----
        bf16x8 af[4], bfr[4];
        #pragma unroll
        for (int m = 0; m < 4; ++m)
            af[m] = *(const bf16x8*)(As + (wr + m * 16 + lr) * 32 + lk);
        #pragma unroll
        for (int n = 0; n < 4; ++n)
            bfr[n] = *(const bf16x8*)(Bs + (wc + n * 16 + lr) * 32 + lk);
        #pragma unroll
        for (int m = 0; m < 4; ++m)
            #pragma unroll
            for (int n = 0; n < 4; ++n)
                acc[m][n] = __builtin_amdgcn_mfma_f32_16x16x32_bf16(af[m], bfr[n], acc[m][n], 0, 0, 0);
        __syncthreads();
    }

    // ---- epilogue: alpha * acc + bias ----
    const float alpha = *alphap;
    float bv[4];
    #pragma unroll
    for (int n = 0; n < 4; ++n) bv[n] = bias[bn0 + wc + n * 16 + lr];

    #pragma unroll
    for (int m = 0; m < 4; ++m) {
        #pragma unroll
        for (int n = 0; n < 4; ++n) {
            const int gcol = bn0 + wc + n * 16 + lr;
            #pragma unroll
            for (int r = 0; r < 4; ++r) {
                const int grow = bm0 + wr + m * 16 + ((lane >> 4) << 2) + r;
                C[(size_t)grow * N + gcol] = alpha * acc[m][n][r] + bv[n];
            }
        }
    }
}

extern "C" void kernel_launch(void* const* d_in, const int* in_sizes, int n_in,
                              void* d_out, int out_size, void* d_ws, size_t ws_size,
                              hipStream_t stream) {
    const float* x     = (const float*)d_in[0];
    const float* w     = (const float*)d_in[1];
    const float* alpha = (const float*)d_in[2];
    const float* bias  = (const float*)d_in[3];
    float* out = (float*)d_out;

    const int wn   = in_sizes[1];        // 1048576
    const int dout = in_sizes[3];        // 1024
    const int din  = wn / dout;          // 1024
    const int m    = in_sizes[0] / din;  // 32768

    char* ws = (char*)d_ws;
    float*  delta = (float*)ws;                 // [0,4)
    double* part  = (double*)(ws + 64);         // 256 doubles
    bf16*   wt    = (bf16*)(ws + 8192);         // 2 MiB ternary weights

    k_abs_part<<<256, 256, 0, stream>>>(w, wn, part);
    k_delta<<<1, 256, 0, stream>>>(part, 256, wn, delta);
    k_quant<<<(wn / 4 + 255) / 256, 256, 0, stream>>>(w, delta, wt, wn / 4);

    dim3 grid((m / 128) * (dout / 128));
    k_gemm<<<grid, 256, 0, stream>>>(x, wt, alpha, bias, out, m, dout, din);
}